// Round 1
// baseline (461.505 us; speedup 1.0000x reference)
//
#include <hip/hip_runtime.h>

#define IN_F 128
#define OUT_F 32

// ---------------------------------------------------------------------------
// Stage 1: degree counting (out-degree of src, in-degree of dst)
// ---------------------------------------------------------------------------
__global__ void degree_kernel(const int* __restrict__ src, const int* __restrict__ dst,
                              int* __restrict__ out_cnt, int* __restrict__ in_cnt,
                              int n_edges) {
    int i = blockIdx.x * blockDim.x + threadIdx.x;
    if (i < n_edges) {
        atomicAdd(&out_cnt[src[i]], 1);
        atomicAdd(&in_cnt[dst[i]], 1);
    }
}

// ---------------------------------------------------------------------------
// Stage 2: tmp[row, col] = (feat[row,:] * rsqrt(max(out_cnt,1))) @ W[:, col]
// 32 lanes per row (one lane per output column), W staged in LDS (16 KB).
// blockDim = 256 -> 8 rows per block.
// ---------------------------------------------------------------------------
__global__ void linear_kernel(const float* __restrict__ feat,
                              const float* __restrict__ weight,
                              const int* __restrict__ out_cnt,
                              float* __restrict__ tmp, int n_nodes) {
    __shared__ float w[IN_F * OUT_F];
    for (int i = threadIdx.x; i < IN_F * OUT_F; i += blockDim.x) w[i] = weight[i];
    __syncthreads();

    const int rows_per_block = 256 / OUT_F;  // 8
    int row = blockIdx.x * rows_per_block + (threadIdx.x >> 5);
    int col = threadIdx.x & (OUT_F - 1);
    if (row >= n_nodes) return;

    float scale = rsqrtf(fmaxf((float)out_cnt[row], 1.0f));
    const float* frow = feat + (size_t)row * IN_F;

    float acc = 0.0f;
#pragma unroll 8
    for (int k = 0; k < IN_F; ++k) {
        acc += frow[k] * w[k * OUT_F + col];
    }
    tmp[(size_t)row * OUT_F + col] = acc * scale;
}

// ---------------------------------------------------------------------------
// Stage 3: scatter-sum: out[dst[e], :] += tmp[src[e], :]  (32 lanes per edge)
// ---------------------------------------------------------------------------
__global__ void scatter_kernel(const int* __restrict__ src, const int* __restrict__ dst,
                               const float* __restrict__ tmp, float* __restrict__ out,
                               int n_edges) {
    long long t = (long long)blockIdx.x * blockDim.x + threadIdx.x;
    int e = (int)(t >> 5);          // t / 32
    int c = (int)(t & (OUT_F - 1)); // t % 32
    if (e < n_edges) {
        int s = src[e];
        int d = dst[e];
        float v = tmp[(size_t)s * OUT_F + c];
        atomicAdd(&out[(size_t)d * OUT_F + c], v);
    }
}

// ---------------------------------------------------------------------------
// Stage 4: out[row, :] *= rsqrt(max(in_cnt,1))
// ---------------------------------------------------------------------------
__global__ void finalize_kernel(float* __restrict__ out, const int* __restrict__ in_cnt,
                                int n_total) {
    int t = blockIdx.x * blockDim.x + threadIdx.x;
    if (t < n_total) {
        int row = t >> 5;  // / OUT_F
        float scale = rsqrtf(fmaxf((float)in_cnt[row], 1.0f));
        out[t] *= scale;
    }
}

extern "C" void kernel_launch(void* const* d_in, const int* in_sizes, int n_in,
                              void* d_out, int out_size, void* d_ws, size_t ws_size,
                              hipStream_t stream) {
    const float* feat   = (const float*)d_in[0];
    const int*   src    = (const int*)d_in[1];
    const int*   dst    = (const int*)d_in[2];
    const float* weight = (const float*)d_in[3];
    float*       out    = (float*)d_out;

    int n_nodes = in_sizes[0] / IN_F;   // 100000
    int n_edges = in_sizes[1];          // 1600000

    // workspace layout: [out_cnt: n_nodes int][in_cnt: n_nodes int][tmp: n_nodes*32 float]
    int*   out_cnt = (int*)d_ws;
    int*   in_cnt  = out_cnt + n_nodes;
    float* tmp     = (float*)(in_cnt + n_nodes);

    hipMemsetAsync(out_cnt, 0, (size_t)2 * n_nodes * sizeof(int), stream);
    hipMemsetAsync(d_out, 0, (size_t)out_size * sizeof(float), stream);

    degree_kernel<<<(n_edges + 255) / 256, 256, 0, stream>>>(src, dst, out_cnt, in_cnt, n_edges);

    linear_kernel<<<(n_nodes + 7) / 8, 256, 0, stream>>>(feat, weight, out_cnt, tmp, n_nodes);

    long long scatter_threads = (long long)n_edges * OUT_F;
    scatter_kernel<<<(int)((scatter_threads + 255) / 256), 256, 0, stream>>>(src, dst, tmp, out, n_edges);

    int n_total = n_nodes * OUT_F;
    finalize_kernel<<<(n_total + 255) / 256, 256, 0, stream>>>(out, in_cnt, n_total);
}

// Round 2
// 331.114 us; speedup vs baseline: 1.3938x; 1.3938x over previous
//
#include <hip/hip_runtime.h>

#define IN_F 128
#define OUT_F 32
#define CSR_STRIDE 64
#define OVF_CAP 2048

// ---------------------------------------------------------------------------
// Stage 1: degrees + padded CSR (counting-sort edges by dst).
// in_cnt doubles as the CSR insertion cursor. Overflow (deg>64, ~impossible
// for Poisson(16) but handled for correctness) goes to a small list.
// ---------------------------------------------------------------------------
__global__ void build_kernel(const int* __restrict__ src, const int* __restrict__ dst,
                             int* __restrict__ out_cnt, int* __restrict__ in_cnt,
                             int* __restrict__ csr, int* __restrict__ ovf,
                             int* __restrict__ ovf_cnt, int n_edges) {
    int e = blockIdx.x * blockDim.x + threadIdx.x;
    if (e >= n_edges) return;
    int s = src[e], d = dst[e];
    atomicAdd(&out_cnt[s], 1);
    int pos = atomicAdd(&in_cnt[d], 1);
    if (pos < CSR_STRIDE) {
        csr[(size_t)d * CSR_STRIDE + pos] = s;
    } else {
        int o = atomicAdd(ovf_cnt, 1);
        if (o < OVF_CAP) { ovf[2 * o] = s; ovf[2 * o + 1] = d; }
    }
}

// ---------------------------------------------------------------------------
// Stage 2: tmp = (feat * outdeg^-1/2) @ W.  Register-blocked 4 rows x 4 cols
// per thread; W staged in LDS (float4 reads broadcast conflict-free: 8
// distinct 16B addrs per wave spanning all 32 banks). float4 global loads.
// Block = 256 threads -> 128 rows/block.
// ---------------------------------------------------------------------------
__global__ __launch_bounds__(256) void linear_kernel(const float* __restrict__ feat,
                                                     const float* __restrict__ weight,
                                                     const int* __restrict__ out_cnt,
                                                     float* __restrict__ tmp, int n_nodes) {
    __shared__ float w[IN_F * OUT_F];
    {
        const float4* wg = (const float4*)weight;
        float4* wsh = (float4*)w;
        for (int i = threadIdx.x; i < IN_F * OUT_F / 4; i += 256) wsh[i] = wg[i];
    }
    __syncthreads();

    int q  = threadIdx.x >> 3;   // row-quad within block: 0..31
    int cg = threadIdx.x & 7;    // col group of 4: 0..7
    int row0 = blockIdx.x * 128 + q * 4;
    if (row0 >= n_nodes) return;
    int rmax = n_nodes - row0;   // valid rows in this quad (1..4)
    if (rmax > 4) rmax = 4;

    const float4* feat4 = (const float4*)feat;
    float4 acc[4];
#pragma unroll
    for (int r = 0; r < 4; ++r) acc[r] = make_float4(0.f, 0.f, 0.f, 0.f);

    for (int k4 = 0; k4 < IN_F / 4; ++k4) {
        float4 wv0 = *(const float4*)&w[(4 * k4 + 0) * OUT_F + 4 * cg];
        float4 wv1 = *(const float4*)&w[(4 * k4 + 1) * OUT_F + 4 * cg];
        float4 wv2 = *(const float4*)&w[(4 * k4 + 2) * OUT_F + 4 * cg];
        float4 wv3 = *(const float4*)&w[(4 * k4 + 3) * OUT_F + 4 * cg];
#pragma unroll
        for (int r = 0; r < 4; ++r) {
            int rr = (r < rmax) ? r : 0;  // clamp tail loads, store is guarded
            float4 f = feat4[(size_t)(row0 + rr) * (IN_F / 4) + k4];
            acc[r].x += f.x * wv0.x + f.y * wv1.x + f.z * wv2.x + f.w * wv3.x;
            acc[r].y += f.x * wv0.y + f.y * wv1.y + f.z * wv2.y + f.w * wv3.y;
            acc[r].z += f.x * wv0.z + f.y * wv1.z + f.z * wv2.z + f.w * wv3.z;
            acc[r].w += f.x * wv0.w + f.y * wv1.w + f.z * wv2.w + f.w * wv3.w;
        }
    }

    float4* tmp4 = (float4*)tmp;
#pragma unroll
    for (int r = 0; r < 4; ++r) {
        if (r < rmax) {
            float sc = rsqrtf(fmaxf((float)out_cnt[row0 + r], 1.0f));
            float4 o = acc[r];
            o.x *= sc; o.y *= sc; o.z *= sc; o.w *= sc;
            tmp4[(size_t)(row0 + r) * (OUT_F / 4) + cg] = o;
        }
    }
}

// ---------------------------------------------------------------------------
// Stage 3: pull-gather. One wave64 per dst node. CSR indices loaded in one
// coalesced 256B read into lane registers, broadcast via shfl. Lanes 0-31
// take even edges, 32-63 odd edges; combine halves with shfl_xor(32).
// In-degree scale fused; single coalesced write. NO float atomics.
// ---------------------------------------------------------------------------
__global__ __launch_bounds__(256) void gather_kernel(const int* __restrict__ csr,
                                                     const int* __restrict__ in_cnt,
                                                     const float* __restrict__ tmp,
                                                     float* __restrict__ out, int n_nodes) {
    int node = (int)(((size_t)blockIdx.x * blockDim.x + threadIdx.x) >> 6);
    int lane = threadIdx.x & 63;
    if (node >= n_nodes) return;

    int cnt_full = in_cnt[node];
    int cnt = min(cnt_full, CSR_STRIDE);

    int idx = 0;
    if (lane < cnt) idx = csr[(size_t)node * CSR_STRIDE + lane];

    int half = lane >> 5;
    int c = lane & 31;
    float v = 0.0f;
    for (int i = 0; 2 * i < cnt; ++i) {
        int j = 2 * i + half;
        int s = __shfl(idx, (j < cnt) ? j : 0, 64);  // uniform participation
        if (j < cnt) v += tmp[(size_t)s * OUT_F + c];
    }
    v += __shfl_xor(v, 32, 64);

    if (lane < 32) {
        float scale = rsqrtf(fmaxf((float)cnt_full, 1.0f));
        out[(size_t)node * OUT_F + c] = v * scale;
    }
}

// ---------------------------------------------------------------------------
// Stage 3b: overflow edges (deg > 64) — expected count 0; correctness only.
// Adds post-scale so it composes with gather's scaled write.
// ---------------------------------------------------------------------------
__global__ void ovf_kernel(const int* __restrict__ ovf, const int* __restrict__ ovf_cnt,
                           const int* __restrict__ in_cnt, const float* __restrict__ tmp,
                           float* __restrict__ out) {
    int t = blockIdx.x * blockDim.x + threadIdx.x;
    int e = t >> 5, c = t & 31;
    int n = min(*ovf_cnt, OVF_CAP);
    if (e < n) {
        int s = ovf[2 * e], d = ovf[2 * e + 1];
        float scale = rsqrtf(fmaxf((float)in_cnt[d], 1.0f));
        atomicAdd(&out[(size_t)d * OUT_F + c], tmp[(size_t)s * OUT_F + c] * scale);
    }
}

// ---------------------------------------------------------------------------
// Fallback path (only if ws too small for CSR): round-1 atomic scatter.
// ---------------------------------------------------------------------------
__global__ void scatter_kernel(const int* __restrict__ src, const int* __restrict__ dst,
                               const float* __restrict__ tmp, float* __restrict__ out,
                               int n_edges) {
    long long t = (long long)blockIdx.x * blockDim.x + threadIdx.x;
    int e = (int)(t >> 5);
    int c = (int)(t & (OUT_F - 1));
    if (e < n_edges) {
        atomicAdd(&out[(size_t)dst[e] * OUT_F + c], tmp[(size_t)src[e] * OUT_F + c]);
    }
}

__global__ void finalize_kernel(float* __restrict__ out, const int* __restrict__ in_cnt,
                                int n_total) {
    int t = blockIdx.x * blockDim.x + threadIdx.x;
    if (t < n_total) {
        out[t] *= rsqrtf(fmaxf((float)in_cnt[t >> 5], 1.0f));
    }
}

__global__ void degree_kernel(const int* __restrict__ src, const int* __restrict__ dst,
                              int* __restrict__ out_cnt, int* __restrict__ in_cnt,
                              int n_edges) {
    int i = blockIdx.x * blockDim.x + threadIdx.x;
    if (i < n_edges) {
        atomicAdd(&out_cnt[src[i]], 1);
        atomicAdd(&in_cnt[dst[i]], 1);
    }
}

extern "C" void kernel_launch(void* const* d_in, const int* in_sizes, int n_in,
                              void* d_out, int out_size, void* d_ws, size_t ws_size,
                              hipStream_t stream) {
    const float* feat   = (const float*)d_in[0];
    const int*   src    = (const int*)d_in[1];
    const int*   dst    = (const int*)d_in[2];
    const float* weight = (const float*)d_in[3];
    float*       out    = (float*)d_out;

    int n_nodes = in_sizes[0] / IN_F;   // 100000
    int n_edges = in_sizes[1];          // 1600000

    // ws layout: [out_cnt n][in_cnt n][ovf_cnt+pad 8][ovf 2*CAP][csr n*64][tmp n*32]
    int*   out_cnt = (int*)d_ws;
    int*   in_cnt  = out_cnt + n_nodes;
    int*   ovf_cnt = in_cnt + n_nodes;
    int*   ovf     = ovf_cnt + 8;
    int*   csr     = ovf + 2 * OVF_CAP;
    float* tmp     = (float*)(csr + (size_t)n_nodes * CSR_STRIDE);
    size_t needed  = (char*)(tmp + (size_t)n_nodes * OUT_F) - (char*)d_ws;

    if (ws_size >= needed) {
        hipMemsetAsync(out_cnt, 0, (size_t)(2 * n_nodes + 8) * sizeof(int), stream);
        build_kernel<<<(n_edges + 255) / 256, 256, 0, stream>>>(
            src, dst, out_cnt, in_cnt, csr, ovf, ovf_cnt, n_edges);
        linear_kernel<<<(n_nodes + 127) / 128, 256, 0, stream>>>(
            feat, weight, out_cnt, tmp, n_nodes);
        gather_kernel<<<(int)(((size_t)n_nodes * 64 + 255) / 256), 256, 0, stream>>>(
            csr, in_cnt, tmp, out, n_nodes);
        ovf_kernel<<<OVF_CAP * 32 / 256, 256, 0, stream>>>(ovf, ovf_cnt, in_cnt, tmp, out);
    } else {
        // fallback: atomic scatter (round-1 structure with improved linear)
        float* tmp_fb = (float*)(ovf + 2 * OVF_CAP);
        hipMemsetAsync(out_cnt, 0, (size_t)(2 * n_nodes + 8) * sizeof(int), stream);
        hipMemsetAsync(d_out, 0, (size_t)out_size * sizeof(float), stream);
        degree_kernel<<<(n_edges + 255) / 256, 256, 0, stream>>>(src, dst, out_cnt, in_cnt, n_edges);
        linear_kernel<<<(n_nodes + 127) / 128, 256, 0, stream>>>(feat, weight, out_cnt, tmp_fb, n_nodes);
        long long st = (long long)n_edges * OUT_F;
        scatter_kernel<<<(int)((st + 255) / 256), 256, 0, stream>>>(src, dst, tmp_fb, out, n_edges);
        finalize_kernel<<<(n_nodes * OUT_F + 255) / 256, 256, 0, stream>>>(out, in_cnt, n_nodes * OUT_F);
    }
}